// Round 6
// baseline (41.220 us; speedup 1.0000x reference)
//
#include <hip/hip_runtime.h>

// Problem constants (fixed by the reference setup)
#define NN   32
#define CCH  2
#define PP   (512*512)       // 262144 pixels per image plane
#define RR   (NN*CCH)        // 64 rows
#define NB   256             // distance-quantization buckets over [0,1]
#define CKS  32              // chunk-blocks per image
#define CHUNK (PP/CKS)       // 8192 pixels per chunk
#define HT   512             // threads per hist block
#define ST   256             // threads per scan block == NB

static_assert(ST == NB, "scan assumes one bucket per thread");
static_assert(CHUNK == HT*16, "hist loop shape");
static_assert(CHUNK < 65536, "packed 16-bit cnt would overflow");
static_assert(RR <= 64, "final reduce assumes one wave");

__device__ __forceinline__ double iou_f(double msum, unsigned k, unsigned cs) {
    if (k == 0u) return 0.0;              // "iou before position 1" is 0
    if (msum == 0.0) return 1.0;          // no ones: inter=0, union=k -> iou=1
    const double dk = (double)k, dcs = (double)cs;
    return 1.0 - (msum - dcs) / (msum + dk - dcs);
}

// Kernel 1: each block histograms one pixel-chunk of image n for BOTH channels
// (targets read once) into packed LDS u32 (cnt<<16|ones), then merges straight
// into the 128 KB global row-histogram with u64 atomics (order-independent
// integer adds -> bit-deterministic). No partial-histogram round trip.
__global__ __launch_bounds__(HT, 8) void hist_kernel(
        const float* __restrict__ x, const int* __restrict__ tgt,
        unsigned long long* __restrict__ g_mhist, unsigned* __restrict__ g_pos)
{
    __shared__ unsigned s_h0[NB];            // 1 KB
    __shared__ unsigned s_h1[NB];            // 1 KB
    __shared__ unsigned s_posr[HT/64][2];

    const int nb  = blockIdx.x;              // 0 .. NN*CKS-1
    const int n   = nb / CKS, ck = nb % CKS;
    const int tid = threadIdx.x;

    if (tid < NB) { s_h0[tid] = 0u; s_h1[tid] = 0u; }
    __syncthreads();

    const float* x0 = x   + ((size_t)(n*CCH + 0))*PP + (size_t)ck*CHUNK;
    const float* x1 = x   + ((size_t)(n*CCH + 1))*PP + (size_t)ck*CHUNK;
    const int*   tr = tgt + (size_t)n*PP            + (size_t)ck*CHUNK;

    // issue ALL 12 dwordx4 loads up front (both 8-px groups), then process
    const int p0 = tid*8, p1 = HT*8 + tid*8;
    const float4 A0 = *reinterpret_cast<const float4*>(x0 + p0);
    const float4 A1 = *reinterpret_cast<const float4*>(x0 + p0 + 4);
    const float4 B0 = *reinterpret_cast<const float4*>(x1 + p0);
    const float4 B1 = *reinterpret_cast<const float4*>(x1 + p0 + 4);
    const int4   T0 = *reinterpret_cast<const int4*>(tr + p0);
    const int4   T1 = *reinterpret_cast<const int4*>(tr + p0 + 4);
    const float4 C0 = *reinterpret_cast<const float4*>(x0 + p1);
    const float4 C1 = *reinterpret_cast<const float4*>(x0 + p1 + 4);
    const float4 D0 = *reinterpret_cast<const float4*>(x1 + p1);
    const float4 D1 = *reinterpret_cast<const float4*>(x1 + p1 + 4);
    const int4   U0 = *reinterpret_cast<const int4*>(tr + p1);
    const int4   U1 = *reinterpret_cast<const int4*>(tr + p1 + 4);

    unsigned pos0 = 0, pos1 = 0;
    auto proc = [&](const float4& a0, const float4& a1,
                    const float4& b0, const float4& b1,
                    const int4& t0, const int4& t1) {
        const float xs0[8] = {a0.x,a0.y,a0.z,a0.w, a1.x,a1.y,a1.z,a1.w};
        const float xs1[8] = {b0.x,b0.y,b0.z,b0.w, b1.x,b1.y,b1.z,b1.w};
        const int   ts [8] = {t0.x,t0.y,t0.z,t0.w, t1.x,t1.y,t1.z,t1.w};
        #pragma unroll
        for (int j = 0; j < 8; ++j) {
            const bool z = (ts[j] == 0);                 // targets are {0,1}
            const float d0 = z ? (1.0f - xs0[j]) : xs0[j];
            const float d1 = z ? xs1[j] : (1.0f - xs1[j]);
            int k0 = (int)(d0 * (float)NB); k0 = k0 > NB-1 ? NB-1 : k0;
            int k1 = (int)(d1 * (float)NB); k1 = k1 > NB-1 ? NB-1 : k1;
            atomicAdd(&s_h0[k0], 0x10000u | (z ? 1u : 0u));
            atomicAdd(&s_h1[k1], 0x10000u | (z ? 0u : 1u));
            pos0 += (xs0[j] > 0.25f) ? 1u : 0u;
            pos1 += (xs1[j] > 0.25f) ? 1u : 0u;
        }
    };
    proc(A0, A1, B0, B1, T0, T1);
    proc(C0, C1, D0, D1, U0, U1);

    for (int off = 32; off; off >>= 1) {
        pos0 += __shfl_down(pos0, off);
        pos1 += __shfl_down(pos1, off);
    }
    if ((tid & 63) == 0) { s_posr[tid>>6][0] = pos0; s_posr[tid>>6][1] = pos1; }
    __syncthreads();                       // also completes LDS hist atomics

    if (tid == 0) {
        unsigned q0 = 0, q1 = 0;
        #pragma unroll
        for (int w = 0; w < HT/64; ++w) { q0 += s_posr[w][0]; q1 += s_posr[w][1]; }
        atomicAdd(&g_pos[n*CCH + 0], q0);
        atomicAdd(&g_pos[n*CCH + 1], q1);
    }
    // merge LDS hist -> global row histogram (1 u64 atomic per thread)
    if (tid < NB) {
        const unsigned v = s_h0[tid];
        atomicAdd(&g_mhist[(size_t)(n*CCH + 0)*NB + tid],
                  ((unsigned long long)(v >> 16) << 32) | (v & 0xffffu));
    } else if (tid < 2*NB) {
        const int i = tid - NB;
        const unsigned v = s_h1[i];
        atomicAdd(&g_mhist[(size_t)(n*CCH + 1)*NB + i],
                  ((unsigned long long)(v >> 16) << 32) | (v & 0xffffu));
    }
}

// Kernel 2: one block per row (n,c). Thread tid owns scan position tid
// (bucket NB-1-tid). Wave-shuffle u64 scan (2 barriers total). Last block
// (ticket) reduces the 64 rows to the final scalar.
__global__ __launch_bounds__(ST) void scan_kernel(
        const unsigned long long* __restrict__ g_mhist,
        const unsigned* __restrict__ g_pos,
        float* __restrict__ g_row, float* __restrict__ g_valid,
        unsigned* __restrict__ g_ticket, float* __restrict__ out)
{
    __shared__ unsigned long long s_wsum[ST/64];
    __shared__ double   s_red[ST/64];
    __shared__ unsigned s_flag;

    const int r = blockIdx.x;
    const int tid = threadIdx.x, lane = tid & 63, wv = tid >> 6;

    const int bk = NB-1 - tid;             // descending distance, position=tid
    const unsigned long long v = g_mhist[(size_t)r*NB + bk];
    const unsigned lc = (unsigned)(v >> 32);
    const unsigned lo = (unsigned)(v & 0xffffffffu);

    // intra-wave inclusive scan of packed (cnt<<32 | ones)
    unsigned long long s = v;
    #pragma unroll
    for (int off = 1; off < 64; off <<= 1) {
        const unsigned long long t = __shfl_up(s, off, 64);
        if (lane >= off) s += t;
    }
    if (lane == 63) s_wsum[wv] = s;
    __syncthreads();
    unsigned long long woff = 0, tot = 0;
    #pragma unroll
    for (int w = 0; w < ST/64; ++w) {
        const unsigned long long u = s_wsum[w];
        tot += u;
        if (w < wv) woff += u;
    }
    const unsigned long long excl = s + woff - v;
    const unsigned msum = (unsigned)(tot & 0xffffffffu);
    const unsigned k  = (unsigned)(excl >> 32);
    const unsigned cs = (unsigned)(excl & 0xffffffffu);

    double acc = 0.0;
    if (lc) {
        const double dmsum = (double)msum;
        const double ip  = iou_f(dmsum, k, cs);
        const double in_ = iou_f(dmsum, k + lc, cs + lo);
        acc = (((double)bk + 0.5) * (1.0/(double)NB)) * (in_ - ip);
    }
    for (int off = 32; off; off >>= 1) acc += __shfl_down(acc, off);
    if (lane == 0) s_red[wv] = acc;
    __syncthreads();
    if (tid == 0) {
        double t = 0.0;
        #pragma unroll
        for (int w = 0; w < ST/64; ++w) t += s_red[w];
        const unsigned pos = g_pos[r];
        const bool valid = !(msum == 0u && pos == 0u);
        const double W[CCH] = {1.428, 40.097};
        g_row[r]   = valid ? (float)(t * W[r % CCH]) : 0.f;
        g_valid[r] = valid ? 1.f : 0.f;
        __threadfence();                   // publish row result device-wide
        s_flag = atomicAdd(g_ticket, 1u);  // device-scope by default
    }
    __syncthreads();

    if (s_flag == RR - 1) {                // last block reduces all rows
        __threadfence();
        if (tid < 64) {
            const volatile float* vr = g_row;
            const volatile float* vv = g_valid;
            double t  = (tid < RR) ? (double)vr[tid] : 0.0;
            double vl = (tid < RR) ? (double)vv[tid] : 0.0;
            for (int off = 32; off; off >>= 1) {
                t  += __shfl_down(t, off);
                vl += __shfl_down(vl, off);
            }
            if (tid == 0) out[0] = (float)(t / (double)NN / vl);
        }
    }
}

extern "C" void kernel_launch(void* const* d_in, const int* in_sizes, int n_in,
                              void* d_out, int out_size, void* d_ws, size_t ws_size,
                              hipStream_t stream) {
    const float* x   = (const float*)d_in[0];
    const int*   tgt = (const int*)d_in[1];
    float* out = (float*)d_out;

    // workspace: [mhist RR*NB u64 | pos RR u32 | ticket 1 u32 | row | valid]
    unsigned long long* g_mhist = (unsigned long long*)d_ws;     // 128 KB
    unsigned* g_pos    = (unsigned*)(g_mhist + (size_t)RR*NB);   // RR u32
    unsigned* g_ticket = g_pos + RR;                             // 1 u32
    float*    g_row    = (float*)(g_ticket + 1);                 // RR floats
    float*    g_valid  = g_row + RR;                             // RR floats

    const size_t ZB = (size_t)RR*NB*8 + RR*4 + 4;  // mhist + pos + ticket
    hipMemsetAsync(d_ws, 0, ZB, stream);
    hist_kernel<<<NN*CKS, HT, 0, stream>>>(x, tgt, g_mhist, g_pos);
    scan_kernel<<<RR, ST, 0, stream>>>(g_mhist, g_pos, g_row, g_valid, g_ticket, out);
}

// Round 7
// 29.772 us; speedup vs baseline: 1.3845x; 1.3845x over previous
//
#include <hip/hip_runtime.h>

// Problem constants (fixed by the reference setup)
#define NN   32
#define CCH  2
#define PP   (512*512)       // 262144 pixels per image plane
#define RR   (NN*CCH)        // 64 rows
#define NB   256             // distance-quantization buckets over [0,1]
#define CKS  32              // chunk-blocks per image
#define CHUNK (PP/CKS)       // 8192 pixels per chunk
#define HT   512             // threads per hist block
#define ST   256             // threads per scan block == NB
#define COLS 32              // per-lane-group histogram columns (bank = lane&31)

static_assert(ST == NB, "scan assumes one bucket per thread");
static_assert(CHUNK == HT*16, "hist loop shape");
static_assert(RR <= 64, "final reduce assumes one wave");

__device__ __forceinline__ double iou_f(double msum, unsigned k, unsigned cs) {
    if (k == 0u) return 0.0;              // "iou before position 1" is 0
    if (msum == 0.0) return 1.0;          // no ones: inter=0, union=k -> iou=1
    const double dk = (double)k, dcs = (double)cs;
    return 1.0 - (msum - dcs) / (msum + dk - dcs);
}

// Kernel 1: per-chunk histogram of both channels (targets read once).
// Bank-conflict-free layout: cell = s_h[(ch*NB + bucket)*32 + (lane&31)]
// -> LDS bank = lane&31 (2 lanes/bank, free). Packed u32 (cnt<<16 | ones).
// Merge columns with rotation (c+tid)&31 (also conflict-free), write one
// partial u32 per (ch,bucket) per block. Pure integer -> bit-deterministic.
__global__ __launch_bounds__(HT, 4) void hist_kernel(
        const float* __restrict__ x, const int* __restrict__ tgt,
        unsigned* __restrict__ g_part, unsigned* __restrict__ g_pos,
        unsigned* __restrict__ g_ticket)
{
    __shared__ unsigned s_h[CCH*NB*COLS];    // 64 KB
    __shared__ unsigned s_posr[HT/64][2];

    const int nb  = blockIdx.x;              // 0 .. NN*CKS-1
    const int n   = nb / CKS, ck = nb % CKS;
    const int tid = threadIdx.x;
    const int col = tid & 31;

    if (nb == 0 && tid == 0) *g_ticket = 0u; // ordered by kernel boundary

    #pragma unroll
    for (int i = 0; i < CCH*NB*COLS/HT; ++i) s_h[i*HT + tid] = 0u;
    __syncthreads();

    const float* x0 = x   + ((size_t)(n*CCH + 0))*PP + (size_t)ck*CHUNK;
    const float* x1 = x   + ((size_t)(n*CCH + 1))*PP + (size_t)ck*CHUNK;
    const int*   tr = tgt + (size_t)n*PP            + (size_t)ck*CHUNK;

    // issue ALL 12 dwordx4 loads up front, then process
    const int p0 = tid*8, p1 = HT*8 + tid*8;
    const float4 A0 = *reinterpret_cast<const float4*>(x0 + p0);
    const float4 A1 = *reinterpret_cast<const float4*>(x0 + p0 + 4);
    const float4 B0 = *reinterpret_cast<const float4*>(x1 + p0);
    const float4 B1 = *reinterpret_cast<const float4*>(x1 + p0 + 4);
    const int4   T0 = *reinterpret_cast<const int4*>(tr + p0);
    const int4   T1 = *reinterpret_cast<const int4*>(tr + p0 + 4);
    const float4 C0 = *reinterpret_cast<const float4*>(x0 + p1);
    const float4 C1 = *reinterpret_cast<const float4*>(x0 + p1 + 4);
    const float4 D0 = *reinterpret_cast<const float4*>(x1 + p1);
    const float4 D1 = *reinterpret_cast<const float4*>(x1 + p1 + 4);
    const int4   U0 = *reinterpret_cast<const int4*>(tr + p1);
    const int4   U1 = *reinterpret_cast<const int4*>(tr + p1 + 4);

    unsigned pos0 = 0, pos1 = 0;
    auto proc = [&](const float4& a0, const float4& a1,
                    const float4& b0, const float4& b1,
                    const int4& t0, const int4& t1) {
        const float xs0[8] = {a0.x,a0.y,a0.z,a0.w, a1.x,a1.y,a1.z,a1.w};
        const float xs1[8] = {b0.x,b0.y,b0.z,b0.w, b1.x,b1.y,b1.z,b1.w};
        const int   ts [8] = {t0.x,t0.y,t0.z,t0.w, t1.x,t1.y,t1.z,t1.w};
        #pragma unroll
        for (int j = 0; j < 8; ++j) {
            const bool z = (ts[j] == 0);                 // targets are {0,1}
            const float d0 = z ? (1.0f - xs0[j]) : xs0[j];
            const float d1 = z ? xs1[j] : (1.0f - xs1[j]);
            int k0 = (int)(d0 * (float)NB); k0 = k0 > NB-1 ? NB-1 : k0;
            int k1 = (int)(d1 * (float)NB); k1 = k1 > NB-1 ? NB-1 : k1;
            atomicAdd(&s_h[(0*NB + k0)*COLS + col], 0x10000u | (z ? 1u : 0u));
            atomicAdd(&s_h[(1*NB + k1)*COLS + col], 0x10000u | (z ? 0u : 1u));
            pos0 += (xs0[j] > 0.25f) ? 1u : 0u;
            pos1 += (xs1[j] > 0.25f) ? 1u : 0u;
        }
    };
    proc(A0, A1, B0, B1, T0, T1);
    proc(C0, C1, D0, D1, U0, U1);

    for (int off = 32; off; off >>= 1) {
        pos0 += __shfl_down(pos0, off);
        pos1 += __shfl_down(pos1, off);
    }
    if ((tid & 63) == 0) { s_posr[tid>>6][0] = pos0; s_posr[tid>>6][1] = pos1; }
    __syncthreads();                       // also completes LDS hist atomics

    if (tid == 0) {
        unsigned q0 = 0, q1 = 0;
        #pragma unroll
        for (int w = 0; w < HT/64; ++w) { q0 += s_posr[w][0]; q1 += s_posr[w][1]; }
        g_pos[nb*CCH + 0] = q0; g_pos[nb*CCH + 1] = q1;
    }

    // merge the 32 columns of this thread's (ch,bucket); rotated -> conflict-free
    {
        const unsigned base = tid * COLS;      // tid == ch*NB + bucket
        unsigned sum = 0;
        #pragma unroll
        for (int c = 0; c < COLS; ++c) sum += s_h[base + ((c + tid) & 31)];
        g_part[(size_t)nb * (CCH*NB) + tid] = sum;   // coalesced
    }
}

// Kernel 2: one block per row (n,c). Thread tid owns scan position tid
// (bucket NB-1-tid): merge the 32 block-partials in registers, wave-shuffle
// u64 scan, accumulate d_mid * (iou_incl - iou_excl) in double.
// Last block (ticket) reduces the 64 rows to the final scalar.
__global__ __launch_bounds__(ST) void scan_kernel(
        const unsigned* __restrict__ g_part, const unsigned* __restrict__ g_pos,
        float* __restrict__ g_row, float* __restrict__ g_valid,
        unsigned* __restrict__ g_ticket, float* __restrict__ out)
{
    __shared__ unsigned long long s_wsum[ST/64];
    __shared__ double   s_red[ST/64];
    __shared__ unsigned s_flag;

    const int r = blockIdx.x;
    const int n = r / CCH, c = r % CCH;
    const int tid = threadIdx.x, lane = tid & 63, wv = tid >> 6;

    const int bk = NB-1 - tid;             // descending distance, position=tid
    unsigned lc = 0, lo = 0;
    #pragma unroll
    for (int b = 0; b < CKS; ++b) {
        const unsigned v = g_part[(size_t)(n*CKS + b)*(CCH*NB) + c*NB + bk];
        lc += v >> 16; lo += v & 0xffffu;
    }

    // intra-wave inclusive scan of packed (cnt<<32 | ones)
    const unsigned long long v =
        ((unsigned long long)lc << 32) | (unsigned long long)lo;
    unsigned long long s = v;
    #pragma unroll
    for (int off = 1; off < 64; off <<= 1) {
        const unsigned long long t = __shfl_up(s, off, 64);
        if (lane >= off) s += t;
    }
    if (lane == 63) s_wsum[wv] = s;
    __syncthreads();
    unsigned long long woff = 0, tot = 0;
    #pragma unroll
    for (int w = 0; w < ST/64; ++w) {
        const unsigned long long u = s_wsum[w];
        tot += u;
        if (w < wv) woff += u;
    }
    const unsigned long long excl = s + woff - v;
    const unsigned msum = (unsigned)(tot & 0xffffffffu);
    const unsigned k  = (unsigned)(excl >> 32);
    const unsigned cs = (unsigned)(excl & 0xffffffffu);

    double acc = 0.0;
    if (lc) {
        const double dmsum = (double)msum;
        const double ip  = iou_f(dmsum, k, cs);
        const double in_ = iou_f(dmsum, k + lc, cs + lo);
        acc = (((double)bk + 0.5) * (1.0/(double)NB)) * (in_ - ip);
    }
    for (int off = 32; off; off >>= 1) acc += __shfl_down(acc, off);
    if (lane == 0) s_red[wv] = acc;
    __syncthreads();
    if (tid == 0) {
        double t = 0.0;
        #pragma unroll
        for (int w = 0; w < ST/64; ++w) t += s_red[w];
        unsigned pos = 0;
        for (int b = 0; b < CKS; ++b) pos += g_pos[(n*CKS + b)*CCH + c];
        const bool valid = !(msum == 0u && pos == 0u);
        const double W[CCH] = {1.428, 40.097};
        g_row[r]   = valid ? (float)(t * W[c]) : 0.f;
        g_valid[r] = valid ? 1.f : 0.f;
        __threadfence();                   // publish row result device-wide
        s_flag = atomicAdd(g_ticket, 1u);  // device-scope by default
    }
    __syncthreads();

    if (s_flag == RR - 1) {                // last block reduces all rows
        __threadfence();
        if (tid < 64) {
            const volatile float* vr = g_row;
            const volatile float* vv = g_valid;
            double t  = (tid < RR) ? (double)vr[tid] : 0.0;
            double vl = (tid < RR) ? (double)vv[tid] : 0.0;
            for (int off = 32; off; off >>= 1) {
                t  += __shfl_down(t, off);
                vl += __shfl_down(vl, off);
            }
            if (tid == 0) out[0] = (float)(t / (double)NN / vl);
        }
    }
}

extern "C" void kernel_launch(void* const* d_in, const int* in_sizes, int n_in,
                              void* d_out, int out_size, void* d_ws, size_t ws_size,
                              hipStream_t stream) {
    const float* x   = (const float*)d_in[0];
    const int*   tgt = (const int*)d_in[1];
    float* out = (float*)d_out;

    // workspace (~2.3 MB): every word written before read -> no memset
    const size_t SZP = (size_t)NN * CKS * CCH * NB;      // partials (u32)
    unsigned* g_part  = (unsigned*)d_ws;
    unsigned* g_pos   = g_part + SZP;                    // NN*CKS*2 u32
    float*    g_row   = (float*)(g_pos + NN*CKS*CCH);    // RR floats
    float*    g_valid = g_row + RR;                      // RR floats
    unsigned* g_ticket = (unsigned*)(g_valid + RR);      // 1 u32

    hist_kernel<<<NN*CKS, HT, 0, stream>>>(x, tgt, g_part, g_pos, g_ticket);
    scan_kernel<<<RR, ST, 0, stream>>>(g_part, g_pos, g_row, g_valid, g_ticket, out);
}

// Round 8
// 27.791 us; speedup vs baseline: 1.4832x; 1.0713x over previous
//
#include <hip/hip_runtime.h>

// Problem constants (fixed by the reference setup)
#define NN   32
#define CCH  2
#define PP   (512*512)       // 262144 pixels per image plane
#define RR   (NN*CCH)        // 64 rows
#define NB   256             // distance-quantization buckets over [0,1]
#define BPI  16              // hist blocks per image
#define GRID (NN*BPI)        // 512 blocks -> 2/CU, all co-resident
#define SPAN (PP/BPI)        // 16384 px per block
#define HT   512             // threads per hist block
#define GRAN (HT*8)          // 4096 px per granule (8 px/thread)
#define NG   (SPAN/GRAN)     // 4 granules, register-prefetched
#define ST   256             // threads per scan block == NB

static_assert(ST == NB, "scan assumes one bucket per thread");
static_assert(HT == 2*NB, "partial writeout shape");
static_assert(NG == 4, "manual prefetch unroll below assumes 4 granules");
static_assert(SPAN < 65536, "packed 16-bit cnt would overflow");
static_assert(RR <= 64, "final reduce assumes one wave");

__device__ __forceinline__ double iou_f(double msum, unsigned k, unsigned cs) {
    if (k == 0u) return 0.0;              // "iou before position 1" is 0
    if (msum == 0.0) return 1.0;          // no ones: inter=0, union=k -> iou=1
    const double dk = (double)k, dcs = (double)cs;
    return 1.0 - (msum - dcs) / (msum + dk - dcs);
}

struct Batch {                            // one granule's data for one thread
    float4 a0, a1;                        // ch0 x, 8 px
    float4 b0, b1;                        // ch1 x, 8 px
    int4   t0, t1;                        // targets, 8 px
};

// Kernel 1: persistent-style hist. Each block owns a contiguous 16384-px
// span of image n; 4 granules with depth-1 register prefetch so HBM loads
// stay in flight during the LDS-atomic phases (no fill/drain bubbles —
// whole grid co-resident). Packed LDS u32 (cnt<<16|ones), one atomic per
// (pixel,channel). Pure integer -> bit-deterministic.
__global__ __launch_bounds__(HT, 4) void hist_kernel(
        const float* __restrict__ x, const int* __restrict__ tgt,
        unsigned* __restrict__ g_part, unsigned* __restrict__ g_pos,
        unsigned* __restrict__ g_ticket)
{
    __shared__ unsigned s_h0[NB];            // 1 KB
    __shared__ unsigned s_h1[NB];            // 1 KB
    __shared__ unsigned s_posr[HT/64][2];

    const int nb  = blockIdx.x;              // 0 .. GRID-1
    const int n   = nb / BPI, blk = nb % BPI;
    const int tid = threadIdx.x;

    if (nb == 0 && tid == 0) *g_ticket = 0u; // ordered by kernel boundary

    if (tid < NB) s_h0[tid] = 0u; else s_h1[tid - NB] = 0u;
    __syncthreads();

    const float* x0 = x   + ((size_t)(n*CCH + 0))*PP + (size_t)blk*SPAN;
    const float* x1 = x   + ((size_t)(n*CCH + 1))*PP + (size_t)blk*SPAN;
    const int*   tr = tgt + (size_t)n*PP            + (size_t)blk*SPAN;

    unsigned pos0 = 0, pos1 = 0;

    auto load = [&](int g) -> Batch {
        Batch b;
        const int p = g*GRAN + tid*8;
        b.a0 = *reinterpret_cast<const float4*>(x0 + p);
        b.a1 = *reinterpret_cast<const float4*>(x0 + p + 4);
        b.b0 = *reinterpret_cast<const float4*>(x1 + p);
        b.b1 = *reinterpret_cast<const float4*>(x1 + p + 4);
        b.t0 = *reinterpret_cast<const int4*>(tr + p);
        b.t1 = *reinterpret_cast<const int4*>(tr + p + 4);
        return b;
    };
    auto proc = [&](const Batch& b) {
        const float xs0[8] = {b.a0.x,b.a0.y,b.a0.z,b.a0.w, b.a1.x,b.a1.y,b.a1.z,b.a1.w};
        const float xs1[8] = {b.b0.x,b.b0.y,b.b0.z,b.b0.w, b.b1.x,b.b1.y,b.b1.z,b.b1.w};
        const int   ts [8] = {b.t0.x,b.t0.y,b.t0.z,b.t0.w, b.t1.x,b.t1.y,b.t1.z,b.t1.w};
        #pragma unroll
        for (int j = 0; j < 8; ++j) {
            const bool z = (ts[j] == 0);                 // targets are {0,1}
            const float d0 = z ? (1.0f - xs0[j]) : xs0[j];
            const float d1 = z ? xs1[j] : (1.0f - xs1[j]);
            int k0 = (int)(d0 * (float)NB); k0 = k0 > NB-1 ? NB-1 : k0;
            int k1 = (int)(d1 * (float)NB); k1 = k1 > NB-1 ? NB-1 : k1;
            atomicAdd(&s_h0[k0], 0x10000u | (z ? 1u : 0u));
            atomicAdd(&s_h1[k1], 0x10000u | (z ? 0u : 1u));
            pos0 += (xs0[j] > 0.25f) ? 1u : 0u;
            pos1 += (xs1[j] > 0.25f) ? 1u : 0u;
        }
    };

    // depth-1 prefetch, fully static (no runtime-indexed register arrays)
    Batch c0 = load(0);
    Batch c1 = load(1);      // in flight while proc(c0) runs
    proc(c0);
    Batch c2 = load(2);
    proc(c1);
    Batch c3 = load(3);
    proc(c2);
    proc(c3);

    for (int off = 32; off; off >>= 1) {
        pos0 += __shfl_down(pos0, off);
        pos1 += __shfl_down(pos1, off);
    }
    if ((tid & 63) == 0) { s_posr[tid>>6][0] = pos0; s_posr[tid>>6][1] = pos1; }
    __syncthreads();                       // also completes LDS hist atomics

    if (tid == 0) {
        unsigned q0 = 0, q1 = 0;
        #pragma unroll
        for (int w = 0; w < HT/64; ++w) { q0 += s_posr[w][0]; q1 += s_posr[w][1]; }
        g_pos[nb*CCH + 0] = q0; g_pos[nb*CCH + 1] = q1;
    }
    // one partial u32 per (ch,bucket) per block; HT == 2*NB -> one store each
    g_part[(size_t)nb*(CCH*NB) + tid] = (tid < NB) ? s_h0[tid] : s_h1[tid - NB];
}

// Kernel 2: one block per row (n,c). Thread tid owns scan position tid
// (bucket NB-1-tid): merge the BPI block-partials in registers, wave-shuffle
// u64 scan, accumulate d_mid * (iou_incl - iou_excl) in double.
// Last block (ticket) reduces the 64 rows to the final scalar.
__global__ __launch_bounds__(ST) void scan_kernel(
        const unsigned* __restrict__ g_part, const unsigned* __restrict__ g_pos,
        float* __restrict__ g_row, float* __restrict__ g_valid,
        unsigned* __restrict__ g_ticket, float* __restrict__ out)
{
    __shared__ unsigned long long s_wsum[ST/64];
    __shared__ double   s_red[ST/64];
    __shared__ unsigned s_flag;

    const int r = blockIdx.x;
    const int n = r / CCH, c = r % CCH;
    const int tid = threadIdx.x, lane = tid & 63, wv = tid >> 6;

    const int bk = NB-1 - tid;             // descending distance, position=tid
    unsigned lc = 0, lo = 0;
    #pragma unroll
    for (int b = 0; b < BPI; ++b) {
        const unsigned v = g_part[(size_t)(n*BPI + b)*(CCH*NB) + c*NB + bk];
        lc += v >> 16; lo += v & 0xffffu;
    }

    // intra-wave inclusive scan of packed (cnt<<32 | ones)
    const unsigned long long v =
        ((unsigned long long)lc << 32) | (unsigned long long)lo;
    unsigned long long s = v;
    #pragma unroll
    for (int off = 1; off < 64; off <<= 1) {
        const unsigned long long t = __shfl_up(s, off, 64);
        if (lane >= off) s += t;
    }
    if (lane == 63) s_wsum[wv] = s;
    __syncthreads();
    unsigned long long woff = 0, tot = 0;
    #pragma unroll
    for (int w = 0; w < ST/64; ++w) {
        const unsigned long long u = s_wsum[w];
        tot += u;
        if (w < wv) woff += u;
    }
    const unsigned long long excl = s + woff - v;
    const unsigned msum = (unsigned)(tot & 0xffffffffu);
    const unsigned k  = (unsigned)(excl >> 32);
    const unsigned cs = (unsigned)(excl & 0xffffffffu);

    double acc = 0.0;
    if (lc) {
        const double dmsum = (double)msum;
        const double ip  = iou_f(dmsum, k, cs);
        const double in_ = iou_f(dmsum, k + lc, cs + lo);
        acc = (((double)bk + 0.5) * (1.0/(double)NB)) * (in_ - ip);
    }
    for (int off = 32; off; off >>= 1) acc += __shfl_down(acc, off);
    if (lane == 0) s_red[wv] = acc;
    __syncthreads();
    if (tid == 0) {
        double t = 0.0;
        #pragma unroll
        for (int w = 0; w < ST/64; ++w) t += s_red[w];
        unsigned pos = 0;
        for (int b = 0; b < BPI; ++b) pos += g_pos[(n*BPI + b)*CCH + c];
        const bool valid = !(msum == 0u && pos == 0u);
        const double W[CCH] = {1.428, 40.097};
        g_row[r]   = valid ? (float)(t * W[c]) : 0.f;
        g_valid[r] = valid ? 1.f : 0.f;
        __threadfence();                   // publish row result device-wide
        s_flag = atomicAdd(g_ticket, 1u);  // device-scope by default
    }
    __syncthreads();

    if (s_flag == RR - 1) {                // last block reduces all rows
        __threadfence();
        if (tid < 64) {
            const volatile float* vr = g_row;
            const volatile float* vv = g_valid;
            double t  = (tid < RR) ? (double)vr[tid] : 0.0;
            double vl = (tid < RR) ? (double)vv[tid] : 0.0;
            for (int off = 32; off; off >>= 1) {
                t  += __shfl_down(t, off);
                vl += __shfl_down(vl, off);
            }
            if (tid == 0) out[0] = (float)(t / (double)NN / vl);
        }
    }
}

extern "C" void kernel_launch(void* const* d_in, const int* in_sizes, int n_in,
                              void* d_out, int out_size, void* d_ws, size_t ws_size,
                              hipStream_t stream) {
    const float* x   = (const float*)d_in[0];
    const int*   tgt = (const int*)d_in[1];
    float* out = (float*)d_out;

    // workspace (~1.1 MB): every word written before read -> no memset
    const size_t SZP = (size_t)GRID * CCH * NB;          // partials (u32)
    unsigned* g_part  = (unsigned*)d_ws;
    unsigned* g_pos   = g_part + SZP;                    // GRID*2 u32
    float*    g_row   = (float*)(g_pos + GRID*CCH);      // RR floats
    float*    g_valid = g_row + RR;                      // RR floats
    unsigned* g_ticket = (unsigned*)(g_valid + RR);      // 1 u32

    hist_kernel<<<GRID, HT, 0, stream>>>(x, tgt, g_part, g_pos, g_ticket);
    scan_kernel<<<RR, ST, 0, stream>>>(g_part, g_pos, g_row, g_valid, g_ticket, out);
}